// Round 5
// baseline (422.253 us; speedup 1.0000x reference)
//
#include <hip/hip_runtime.h>

typedef unsigned short ushort_t;
typedef unsigned int uint_t;

using short8 = __attribute__((ext_vector_type(8))) short;
using f32x4  = __attribute__((ext_vector_type(4))) float;

#define N_BATCH   64
#define C_MID     256
#define H_OUT     28
#define W_OUT     28
#define SPATIAL   (H_OUT*W_OUT)
#define OUT_ELEMS (N_BATCH*C_MID*SPATIAL)   // 12,845,056

// histogram: 2048 bins over [-16,16), width 1/64
#define NBINS 2048
#define BIN_LO (-16.0f)
#define BIN_INV 64.0f
#define BIN_W  0.015625f

// padded channels-last geometry (u16 element units)
#define XT_ROW   (57*128)        // 7296
#define XT_IMG   (57*57*128)     // 415872
#define O1_ROW   (30*256)        // 7680
#define O1_IMG   (30*30*256)     // 230400

__device__ __forceinline__ ushort_t f2bf(float f) {
    uint_t u = __float_as_uint(f);
    u += 0x7FFFu + ((u >> 16) & 1u);
    return (ushort_t)(u >> 16);
}

__device__ __forceinline__ void gll16(const ushort_t* g, void* l) {
    __builtin_amdgcn_global_load_lds(
        (const __attribute__((address_space(1))) unsigned int*)g,
        (__attribute__((address_space(3))) unsigned int*)l, 16, 0, 0);
}

// ---------------------------------------------------------------------------
// Zero only the border cells of xT (row0, col0) and o1T (rows 0/29, cols 0/29).
// ---------------------------------------------------------------------------
__global__ __launch_bounds__(256) void zero_borders(
    uint_t* __restrict__ xT32, uint_t* __restrict__ o1T32)
{
    int i = blockIdx.x * 256 + threadIdx.x;
    int n = blockIdx.y;
    if (i >= 22080) return;
    if (i < 7232) {
        uint_t* base = xT32 + (size_t)n * (XT_IMG / 2);
        if (i < 3648) base[i] = 0;                              // row 0
        else { int j = i - 3648; int r = (j >> 6) + 1;          // col 0, rows 1..56
               base[r * (XT_ROW / 2) + (j & 63)] = 0; }
    } else {
        int k = i - 7232;
        uint_t* base = o1T32 + (size_t)n * (O1_IMG / 2);
        if (k < 3840) base[k] = 0;                              // row 0
        else if (k < 7680) base[29 * (O1_ROW / 2) + (k - 3840)] = 0;  // row 29
        else if (k < 11264) { int j = k - 7680; int r = (j >> 7) + 1;
               base[r * (O1_ROW / 2) + (j & 127)] = 0; }        // col 0
        else { int j = k - 11264; int r = (j >> 7) + 1;
               base[r * (O1_ROW / 2) + 29 * 128 + (j & 127)] = 0; } // col 29
    }
}

// ---------------------------------------------------------------------------
// Weight transform: wT1[co][(kh*3+kw)*128+ci] ; wT2[co][k] with k<2304 from w2
// ((kh*3+kw)*256+ci) and k in [2304,2432) = wid[co][ci].  bf16.
// ---------------------------------------------------------------------------
__global__ __launch_bounds__(256) void wtrans(
    const float* __restrict__ w1, const float* __restrict__ w2,
    const float* __restrict__ wid, ushort_t* __restrict__ wT1,
    ushort_t* __restrict__ wT2)
{
    int idx = blockIdx.x * 256 + threadIdx.x;
    if (idx < 256 * 1152) {
        int co = idx / 1152, k = idx % 1152;
        int g = k >> 7, ci = k & 127;
        wT1[idx] = f2bf(w1[(co * 128 + ci) * 9 + g]);
    }
    if (idx < 256 * 2432) {
        int co = idx / 2432, k = idx % 2432;
        float v;
        if (k < 2304) { int g = k >> 8, ci = k & 255; v = w2[(co * 256 + ci) * 9 + g]; }
        else          { v = wid[co * 128 + (k - 2304)]; }
        wT2[idx] = f2bf(v);
    }
}

// ---------------------------------------------------------------------------
// x transform: NCHW f32 -> padded channels-last bf16 xT[n][1+ih][1+iw][ci]
// ---------------------------------------------------------------------------
__global__ __launch_bounds__(256) void xtrans(
    const float* __restrict__ x, ushort_t* __restrict__ xT)
{
    __shared__ ushort_t t[224 * 130];
    const int tid = threadIdx.x;
    const int g = blockIdx.x, n = blockIdx.y;
    const float* xs = x + ((size_t)n * 128) * 3136 + g * 4 * 56;

    for (int it = 0; it < 112; ++it) {
        int f = it * 256 + tid;
        int ci = f / 224, rem = f % 224;
        t[rem * 130 + ci] = f2bf(xs[ci * 3136 + rem]);
    }
    __syncthreads();
    ushort_t* xo = xT + (size_t)n * XT_IMG + (g * 4 + 1) * XT_ROW + 128;
    for (int it = 0; it < 56; ++it) {
        int f = it * 256 + tid;
        int pos = f >> 6, c2 = f & 63;
        int r = pos / 56, iw = pos % 56;
        uint_t v = *(const uint_t*)&t[pos * 130 + c2 * 2];
        *(uint_t*)(xo + r * XT_ROW + iw * 128 + c2 * 2) = v;
    }
}

// ---------------------------------------------------------------------------
// conv1, patch-based. Block = 128co x 224pos (8 rows), 4 waves 64co x 112pos.
// Per ci-chunk of 32: stage 17row x 57col x 32ci stride-2 patch (even/odd
// column split for conflict-free tap reads); 9 taps x K=32 each. A (8KB/tap)
// double-buffered, prefetched one tap ahead. Hist overlaid on A region in
// the epilogue. LDS = 16 + 64 = 80 KB -> 2 blocks/CU.
// ---------------------------------------------------------------------------
__global__ __launch_bounds__(256, 2) void conv1_mfma(
    const ushort_t* __restrict__ xT, const ushort_t* __restrict__ wT1,
    ushort_t* __restrict__ o1T, ushort_t* __restrict__ bh)
{
    const int bx = blockIdx.x;           // n*4 + rg
    const int by = blockIdx.y;
    const int tid = threadIdx.x;
    const int wv = tid >> 6, lane = tid & 63;
    const int ln = lane & 15, quad = lane >> 4;
    const int n = bx >> 2, rg = bx & 3, r0 = rg * 8;
    const int coh = wv & 1, pt = wv >> 1;

    __shared__ short8 Ald[1024];         // 16 KB: 2 bufs x 512
    __shared__ short8 Bp[4096];          // 64 KB patch [k8 4][dr 17][j 57] (+pad)

    f32x4 acc[4][7];
    #pragma unroll
    for (int a = 0; a < 4; ++a)
        #pragma unroll
        for (int b = 0; b < 7; ++b) acc[a][b] = (f32x4){0.f, 0.f, 0.f, 0.f};

    // per-b position constants
    int drb[7], cl0[7], hlog[7];
    #pragma unroll
    for (int b = 0; b < 7; ++b) {
        int p = b * 16 + ln;
        int hloc = pt * 4 + p / 28;      // 0..7
        hlog[b] = r0 + hloc;
        drb[b] = 2 * hloc;               // + kh at use
        cl0[b] = p % 28;
    }

    // patch staging: 64 wave-insts, 16 per wave; slot = (i*4+wv)*64+lane
    uint_t poff[16];
    #pragma unroll
    for (int i = 0; i < 16; ++i) {
        int slot = (i * 4 + wv) * 64 + lane;
        int s2 = min(slot, 3875);
        int k8 = s2 / 969;               // 969 = 17*57
        int rem = s2 - k8 * 969;
        int dr = rem / 57, j = rem - dr * 57;
        int col = (j < 29) ? (2 * j) : (2 * (j - 29) + 1);
        int row = min(2 * r0 + dr, 56);
        poff[i] = (uint_t)(row * XT_ROW + col * 128 + k8 * 8);
    }
    // A staging: 8 wave-insts, 2 per wave; inst = wv*2+jj
    uint_t aoff[2];
    #pragma unroll
    for (int jj = 0; jj < 2; ++jj) {
        int inst = wv * 2 + jj;
        int co = (inst & 1) * 64 + lane;
        aoff[jj] = (uint_t)((by * 128 + co) * 1152 + (inst >> 1) * 8);
    }

    const ushort_t* xTimg = xT + (size_t)n * XT_IMG;

    auto stageA = [&](int tap, int c, int buf) {
        #pragma unroll
        for (int jj = 0; jj < 2; ++jj)
            gll16(wT1 + aoff[jj] + tap * 128 + c * 32,
                  (char*)Ald + buf * 8192 + (wv * 2 + jj) * 1024);
    };

    int st = 0;
    for (int c = 0; c < 4; ++c) {
        #pragma unroll
        for (int i = 0; i < 16; ++i)
            gll16(xTimg + poff[i] + c * 32, (char*)Bp + (i * 4 + wv) * 1024);
        if (c == 0) stageA(0, 0, 0);
        __syncthreads();

        for (int t = 0; t < 9; ++t) {
            const int buf = st & 1;
            if (t < 8)      stageA(t + 1, c, buf ^ 1);
            else if (c < 3) stageA(0, c + 1, buf ^ 1);
            const int kh = t / 3, kw = t - kh * 3;
            short8 af[4], bf[7];
            #pragma unroll
            for (int a = 0; a < 4; ++a)
                af[a] = Ald[buf * 512 + quad * 128 + coh * 64 + a * 16 + ln];
            #pragma unroll
            for (int b = 0; b < 7; ++b) {
                int dr = drb[b] + kh;
                int j = (kw == 1) ? (29 + cl0[b]) : (cl0[b] + (kw >> 1));
                bf[b] = Bp[(quad * 17 + dr) * 57 + j];
            }
            #pragma unroll
            for (int a = 0; a < 4; ++a)
                #pragma unroll
                for (int b = 0; b < 7; ++b)
                    acc[a][b] = __builtin_amdgcn_mfma_f32_16x16x32_bf16(
                        af[a], bf[b], acc[a][b], 0, 0, 0);
            ++st;
            __syncthreads();
        }
    }

    // epilogue: hist overlaid on Ald; clamp -> bf16 o1T (padded channels-last)
    uint_t* hist = (uint_t*)Ald;
    for (int i = tid; i < NBINS; i += 256) hist[i] = 0;
    __syncthreads();

    ushort_t* oimg = o1T + (size_t)n * O1_IMG;
    #pragma unroll
    for (int a = 0; a < 4; ++a) {
        int co = by * 128 + coh * 64 + a * 16 + quad * 4;
        #pragma unroll
        for (int b = 0; b < 7; ++b) {
            if (hlog[b] <= 27) {
                ushort_t pk[4];
                #pragma unroll
                for (int r = 0; r < 4; ++r) {
                    float v = acc[a][b][r];
                    int bin = (int)((v - BIN_LO) * BIN_INV);
                    bin = min(max(bin, 0), NBINS - 1);
                    atomicAdd(&hist[bin], 1u);
                    pk[r] = f2bf(fminf(fmaxf(v, 0.f), 1.f));
                }
                uint2 u; u.x = (uint_t)pk[0] | ((uint_t)pk[1] << 16);
                u.y = (uint_t)pk[2] | ((uint_t)pk[3] << 16);
                *(uint2*)(oimg + ((hlog[b] + 1) * 30 + (cl0[b] + 1)) * 256 + co) = u;
            }
        }
    }

    __syncthreads();
    size_t blin = (size_t)(by * 256 + bx) * NBINS;
    for (int i = tid; i < NBINS; i += 256) bh[blin + i] = (ushort_t)hist[i];
}

// ---------------------------------------------------------------------------
// conv2 + fused identity, 8-row blocks (as R4; hist overlaid on Ad).
// ---------------------------------------------------------------------------
__global__ __launch_bounds__(256, 2) void conv2_mfma(
    const ushort_t* __restrict__ o1T, const ushort_t* __restrict__ xT,
    const ushort_t* __restrict__ wT2, float* __restrict__ fout,
    ushort_t* __restrict__ bh)
{
    const int bx = blockIdx.x;           // n*4 + rg
    const int by = blockIdx.y;
    const int tid = threadIdx.x;
    const int wv = tid >> 6, lane = tid & 63;
    const int ln = lane & 15, quad = lane >> 4;
    const int n = bx >> 2, rg = bx & 3, r0 = rg * 8;
    const int coh = wv & 1;
    const int pt  = wv >> 1;

    __shared__ short8 Ad[2 * 1024];      // 32 KB [buf][k8][co]
    __shared__ short8 Bp[2560];          // 40 KB patch [ci8][dr 10][col 32]

    f32x4 acc[4][7];
    #pragma unroll
    for (int a = 0; a < 4; ++a)
        #pragma unroll
        for (int b = 0; b < 7; ++b) acc[a][b] = (f32x4){0.f, 0.f, 0.f, 0.f};

    int prb[7], cl0[7], hlog[7];
    #pragma unroll
    for (int b = 0; b < 7; ++b) {
        int p = b * 16 + ln;
        int h = r0 + pt * 4 + p / 28;
        hlog[b] = h;
        prb[b] = (min(h, 27) - r0) * 32;
        cl0[b] = p % 28;
    }

    uint_t po[10];
    #pragma unroll
    for (int jj = 0; jj < 10; ++jj) {
        int f = (wv * 10 + jj) * 64 + lane;
        int ci8 = f / 320, rem = f % 320;
        int dr = rem >> 5, cl = rem & 31;
        po[jj] = (uint_t)(min(r0 + dr, 29) * O1_ROW + cl * 256 + ci8 * 8);
    }
    uint_t io[7];
    #pragma unroll
    for (int jj = 0; jj < 7; ++jj) {
        int f = (wv * 7 + jj) * 64 + lane;
        int ci8 = f / 224, pos = f % 224;
        int h = min(r0 + pos / 28, 27), w = pos % 28;
        io[jj] = (uint_t)(((2 * h + 1) * 57 + (2 * w + 1)) * 128 + ci8 * 8);
    }

    const ushort_t* Abase = wT2 + (size_t)(by * 128 + lane) * 2432;
    const ushort_t* o1img = o1T + (size_t)n * O1_IMG;
    const ushort_t* xTimg = xT + (size_t)n * XT_IMG;

    auto stageA = [&](int k0, int buf) {
        #pragma unroll
        for (int j = 0; j < 4; ++j)
            gll16(Abase + (j & 1) * 64 * 2432 + (wv * 2 + (j >> 1)) * 8 + k0,
                  (char*)Ad + buf * 16384 + (wv * 4 + j) * 1024);
    };

    for (int c = 0; c < 4; ++c) {
        #pragma unroll
        for (int jj = 0; jj < 10; ++jj)
            gll16(o1img + po[jj] + c * 64, (char*)Bp + (wv * 10 + jj) * 1024);
        if (c == 0) stageA(0, 0);
        __syncthreads();

        for (int t = 0; t < 9; ++t) {
            const int as = c * 9 + t;
            if (t < 8)      stageA((t + 1) * 256 + c * 64, (as + 1) & 1);
            else if (c < 3) stageA(c * 64 + 64, (as + 1) & 1);
            else            stageA(2304, (as + 1) & 1);
            const int ab = (as & 1) * 1024;
            const int kh = t / 3, kw = t - kh * 3;
            #pragma unroll
            for (int kk = 0; kk < 2; ++kk) {
                short8 af[4], bf[7];
                #pragma unroll
                for (int a = 0; a < 4; ++a)
                    af[a] = Ad[ab + (kk * 4 + quad) * 128 + coh * 64 + a * 16 + ln];
                #pragma unroll
                for (int b = 0; b < 7; ++b)
                    bf[b] = Bp[(kk * 4 + quad) * 320 + prb[b] + kh * 32 + cl0[b] + kw];
                #pragma unroll
                for (int a = 0; a < 4; ++a)
                    #pragma unroll
                    for (int b = 0; b < 7; ++b)
                        acc[a][b] = __builtin_amdgcn_mfma_f32_16x16x32_bf16(
                            af[a], bf[b], acc[a][b], 0, 0, 0);
            }
            __syncthreads();
        }
    }

    for (int cid = 0; cid < 2; ++cid) {
        #pragma unroll
        for (int jj = 0; jj < 7; ++jj)
            gll16(xTimg + io[jj] + cid * 64, (char*)Bp + (wv * 7 + jj) * 1024);
        __syncthreads();
        if (cid == 0) stageA(2368, 1);
        const int ab = ((36 + cid) & 1) * 1024;
        #pragma unroll
        for (int kk = 0; kk < 2; ++kk) {
            short8 af[4], bf[7];
            #pragma unroll
            for (int a = 0; a < 4; ++a)
                af[a] = Ad[ab + (kk * 4 + quad) * 128 + coh * 64 + a * 16 + ln];
            #pragma unroll
            for (int b = 0; b < 7; ++b)
                bf[b] = Bp[(kk * 4 + quad) * 224 + pt * 112 + b * 16 + ln];
            #pragma unroll
            for (int a = 0; a < 4; ++a)
                #pragma unroll
                for (int b = 0; b < 7; ++b)
                    acc[a][b] = __builtin_amdgcn_mfma_f32_16x16x32_bf16(
                        af[a], bf[b], acc[a][b], 0, 0, 0);
        }
        __syncthreads();
    }

    // epilogue: hist overlaid on Ad; clamp -> f32 out (NCHW)
    uint_t* hist = (uint_t*)Ad;
    for (int i = tid; i < NBINS; i += 256) hist[i] = 0;
    __syncthreads();

    #pragma unroll
    for (int a = 0; a < 4; ++a) {
        int co = by * 128 + coh * 64 + a * 16 + quad * 4;
        #pragma unroll
        for (int b = 0; b < 7; ++b) {
            if (hlog[b] <= 27) {
                #pragma unroll
                for (int r = 0; r < 4; ++r) {
                    float v = acc[a][b][r];
                    int bin = (int)((v - BIN_LO) * BIN_INV);
                    bin = min(max(bin, 0), NBINS - 1);
                    atomicAdd(&hist[bin], 1u);
                    fout[((size_t)(n * 256 + co + r)) * SPATIAL +
                         hlog[b] * 28 + cl0[b]] = fminf(fmaxf(v, 0.f), 1.f);
                }
            }
        }
    }

    __syncthreads();
    size_t blin = (size_t)(by * 256 + bx) * NBINS;
    for (int i = tid; i < NBINS; i += 256) bh[blin + i] = (ushort_t)hist[i];
}

// ---------------------------------------------------------------------------
// Reduce nblk per-block u16 histograms -> final u32 histogram
// ---------------------------------------------------------------------------
__global__ __launch_bounds__(256) void hreduce(
    const ushort_t* __restrict__ bh, uint_t* __restrict__ hf, int nblk)
{
    __shared__ uint_t p[256];
    int b0 = blockIdx.x * 64;
    int binl = threadIdx.x & 63, grp = threadIdx.x >> 6;
    uint_t s = 0;
    for (int j = grp; j < nblk; j += 4) s += bh[(size_t)j * NBINS + b0 + binl];
    p[threadIdx.x] = s;
    __syncthreads();
    if (threadIdx.x < 64)
        hf[b0 + threadIdx.x] = p[threadIdx.x] + p[64 + threadIdx.x] +
                               p[128 + threadIdx.x] + p[192 + threadIdx.x];
}

// ---------------------------------------------------------------------------
// Select 99 percentile values from the 2048-bin histogram
// ---------------------------------------------------------------------------
__global__ __launch_bounds__(1024) void select_k(
    const uint_t* __restrict__ hf, float* __restrict__ outp)
{
    __shared__ uint_t cs[1024];
    int t = threadIdx.x;
    uint_t s = hf[2 * t] + hf[2 * t + 1];
    cs[t] = s;
    __syncthreads();
    for (int d = 1; d < 1024; d <<= 1) {
        uint_t v = (t >= d) ? cs[t - d] : 0;
        __syncthreads();
        cs[t] += v;
        __syncthreads();
    }
    if (t >= 1 && t <= 99) {
        long long k = 1 + (long long)llrint(0.01 * (double)t * (double)(OUT_ELEMS - 1));
        int lo = 0, hi = 1023;
        while (lo < hi) { int mid = (lo + hi) >> 1; if ((long long)cs[mid] < k) lo = mid + 1; else hi = mid; }
        long long cum = (lo == 0) ? 0 : (long long)cs[lo - 1];
        int b = lo * 2;
        while (cum + (long long)hf[b] < k) { cum += hf[b]; ++b; }
        outp[t - 1] = BIN_LO + ((float)b + 0.5f) * BIN_W;
    }
}

// ---------------------------------------------------------------------------
extern "C" void kernel_launch(void* const* d_in, const int* in_sizes, int n_in,
                              void* d_out, int out_size, void* d_ws, size_t ws_size,
                              hipStream_t stream)
{
    const float* x   = (const float*)d_in[0];
    const float* w1  = (const float*)d_in[1];
    const float* w2  = (const float*)d_in[2];
    const float* wid = (const float*)d_in[3];
    float* out = (float*)d_out;

    char* ws = (char*)d_ws;
    ushort_t* xT  = (ushort_t*)ws;                         // 53,231,616 B (+4K pad)
    ushort_t* o1T = (ushort_t*)(ws + 53235712);            // 29,491,200 B (+4K pad)
    ushort_t* wT1 = (ushort_t*)(ws + 82731008);            //    589,824 B
    ushort_t* wT2 = (ushort_t*)(ws + 83320832);            //  1,245,184 B
    ushort_t* bh  = (ushort_t*)(ws + 84566016);            //  3,670,016 B
    uint_t*   hf  = (uint_t*)  (ws + 88236032);            //      8,192 B

    zero_borders<<<dim3(87, 64), 256, 0, stream>>>((uint_t*)xT, (uint_t*)o1T);
    wtrans<<<2432, 256, 0, stream>>>(w1, w2, wid, wT1, wT2);
    xtrans<<<dim3(14, 64), 256, 0, stream>>>(x, xT);

    conv1_mfma<<<dim3(256, 2), 256, 0, stream>>>(xT, wT1, o1T, bh);
    hreduce<<<32, 256, 0, stream>>>(bh, hf, 512);
    select_k<<<1, 1024, 0, stream>>>(hf, out + OUT_ELEMS);

    conv2_mfma<<<dim3(256, 2), 256, 0, stream>>>(o1T, xT, wT2, out, bh);
    hreduce<<<32, 256, 0, stream>>>(bh, hf, 512);
    select_k<<<1, 1024, 0, stream>>>(hf, out + OUT_ELEMS + 99);
}

// Round 6
// 404.627 us; speedup vs baseline: 1.0436x; 1.0436x over previous
//
#include <hip/hip_runtime.h>

typedef unsigned short ushort_t;
typedef unsigned int uint_t;

using short8 = __attribute__((ext_vector_type(8))) short;
using f32x4  = __attribute__((ext_vector_type(4))) float;

#define N_BATCH   64
#define C_MID     256
#define H_OUT     28
#define W_OUT     28
#define SPATIAL   (H_OUT*W_OUT)
#define OUT_ELEMS (N_BATCH*C_MID*SPATIAL)   // 12,845,056

// histogram: 2048 bins over [-16,16), width 1/64
#define NBINS 2048
#define BIN_LO (-16.0f)
#define BIN_INV 64.0f
#define BIN_W  0.015625f

// padded channels-last geometry (u16 element units)
#define XT_ROW   (57*128)        // 7296
#define XT_IMG   (57*57*128)     // 415872
#define O1_ROW   (30*256)        // 7680
#define O1_IMG   (30*30*256)     // 230400

__device__ __forceinline__ ushort_t f2bf(float f) {
    uint_t u = __float_as_uint(f);
    u += 0x7FFFu + ((u >> 16) & 1u);
    return (ushort_t)(u >> 16);
}

__device__ __forceinline__ void gll16(const ushort_t* g, void* l) {
    __builtin_amdgcn_global_load_lds(
        (const __attribute__((address_space(1))) unsigned int*)g,
        (__attribute__((address_space(3))) unsigned int*)l, 16, 0, 0);
}

// ---------------------------------------------------------------------------
// Merged: zero borders of xT/o1T (blocks x<87) + weight transform (x>=87).
// wT1[co][(kh*3+kw)*128+ci] ; wT2[co][k], k<2304 from w2, k>=2304 = wid.
// ---------------------------------------------------------------------------
__global__ __launch_bounds__(256) void zwtrans(
    uint_t* __restrict__ xT32, uint_t* __restrict__ o1T32,
    const float* __restrict__ w1, const float* __restrict__ w2,
    const float* __restrict__ wid, ushort_t* __restrict__ wT1,
    ushort_t* __restrict__ wT2)
{
    const int bxx = blockIdx.x, y = blockIdx.y, tid = threadIdx.x;
    if (bxx < 87) {
        int i = bxx * 256 + tid;
        int n = y;
        if (i >= 22080) return;
        if (i < 7232) {
            uint_t* base = xT32 + (size_t)n * (XT_IMG / 2);
            if (i < 3648) base[i] = 0;                              // row 0
            else { int j = i - 3648; int r = (j >> 6) + 1;          // col 0
                   base[r * (XT_ROW / 2) + (j & 63)] = 0; }
        } else {
            int k = i - 7232;
            uint_t* base = o1T32 + (size_t)n * (O1_IMG / 2);
            if (k < 3840) base[k] = 0;                              // row 0
            else if (k < 7680) base[29 * (O1_ROW / 2) + (k - 3840)] = 0;
            else if (k < 11264) { int j = k - 7680; int r = (j >> 7) + 1;
                   base[r * (O1_ROW / 2) + (j & 127)] = 0; }        // col 0
            else { int j = k - 11264; int r = (j >> 7) + 1;
                   base[r * (O1_ROW / 2) + 29 * 128 + (j & 127)] = 0; }
        }
    } else {
        int idx = ((bxx - 87) * 64 + y) * 256 + tid;   // 0..622591
        if (idx < 256 * 1152) {
            int co = idx / 1152, k = idx % 1152;
            int g = k >> 7, ci = k & 127;
            wT1[idx] = f2bf(w1[(co * 128 + ci) * 9 + g]);
        }
        if (idx < 256 * 2432) {
            int co = idx / 2432, k = idx % 2432;
            float v;
            if (k < 2304) { int g = k >> 8, ci = k & 255; v = w2[(co * 256 + ci) * 9 + g]; }
            else          { v = wid[co * 128 + (k - 2304)]; }
            wT2[idx] = f2bf(v);
        }
    }
}

// ---------------------------------------------------------------------------
// x transform: NCHW f32 -> padded channels-last bf16 xT[n][1+ih][1+iw][ci]
// ---------------------------------------------------------------------------
__global__ __launch_bounds__(256) void xtrans(
    const float* __restrict__ x, ushort_t* __restrict__ xT)
{
    __shared__ ushort_t t[224 * 130];
    const int tid = threadIdx.x;
    const int g = blockIdx.x, n = blockIdx.y;
    const float* xs = x + ((size_t)n * 128) * 3136 + g * 4 * 56;

    for (int it = 0; it < 112; ++it) {
        int f = it * 256 + tid;
        int ci = f / 224, rem = f % 224;
        t[rem * 130 + ci] = f2bf(xs[ci * 3136 + rem]);
    }
    __syncthreads();
    ushort_t* xo = xT + (size_t)n * XT_IMG + (g * 4 + 1) * XT_ROW + 128;
    for (int it = 0; it < 56; ++it) {
        int f = it * 256 + tid;
        int pos = f >> 6, c2 = f & 63;
        int r = pos / 56, iw = pos % 56;
        uint_t v = *(const uint_t*)&t[pos * 130 + c2 * 2];
        *(uint_t*)(xo + r * XT_ROW + iw * 128 + c2 * 2) = v;
    }
}

// ---------------------------------------------------------------------------
// conv1, full-co blocks. Block = 256co x 112pos (4 rows), grid 448 (n x rg).
// 4 waves, each 64co x 112pos (a=4, b=7). Per ci-chunk of 32: stage a
// 9row x 57col x 32ci stride-2 patch (36 KB, even/odd column split) shared
// by all 256 couts; 9 taps x K=32. A (16 KB/tap, from L2-resident wT1)
// double-buffered with 1-tap lookahead. LDS 68 KB -> 2 blocks/CU.
// ---------------------------------------------------------------------------
__global__ __launch_bounds__(256, 2) void conv1_mfma(
    const ushort_t* __restrict__ xT, const ushort_t* __restrict__ wT1,
    ushort_t* __restrict__ o1T, ushort_t* __restrict__ bh)
{
    const int bx = blockIdx.x;           // n*7 + rg
    const int tid = threadIdx.x;
    const int wv = tid >> 6, lane = tid & 63;
    const int ln = lane & 15, quad = lane >> 4;
    const int n = bx / 7, rg = bx % 7, r0 = rg * 4;

    __shared__ short8 Ald[2 * 1024];     // 32 KB  [buf][k8 4][co 256]
    __shared__ short8 Bp[2304];          // 36 KB  [k8 4][dr 9][j 57] (513/plane)

    f32x4 acc[4][7];
    #pragma unroll
    for (int a = 0; a < 4; ++a)
        #pragma unroll
        for (int b = 0; b < 7; ++b) acc[a][b] = (f32x4){0.f, 0.f, 0.f, 0.f};

    // per-b position constants
    int drb[7], cl0[7];
    #pragma unroll
    for (int b = 0; b < 7; ++b) {
        int p = b * 16 + ln;
        drb[b] = 2 * (p / 28);           // + kh at use
        cl0[b] = p % 28;
    }

    // patch staging: 36 insts, 9/wave; inst = i*4+wv; slot = inst*64+lane
    uint_t poff[9];
    #pragma unroll
    for (int i = 0; i < 9; ++i) {
        int slot = (i * 4 + wv) * 64 + lane;
        int s2 = min(slot, 2051);
        int k8 = s2 / 513;
        int rem = s2 - k8 * 513;
        int dr = rem / 57, j = rem - dr * 57;
        int col = (j < 29) ? (2 * j) : (2 * (j - 29) + 1);
        poff[i] = (uint_t)((2 * r0 + dr) * XT_ROW + col * 128 + k8 * 8);
    }
    // A staging: 16 insts, 4/wave; wave wv covers co in [wv*64, wv*64+64)
    const uint_t aoff = (uint_t)((wv * 64 + lane) * 1152);

    const ushort_t* xTimg = xT + (size_t)n * XT_IMG;

    auto stageA = [&](int tap, int c, int buf) {
        #pragma unroll
        for (int jj = 0; jj < 4; ++jj)
            gll16(wT1 + aoff + jj * 8 + tap * 128 + c * 32,
                  (char*)Ald + buf * 16384 + (jj * 256 + wv * 64) * 16);
    };

    for (int c = 0; c < 4; ++c) {
        #pragma unroll
        for (int i = 0; i < 9; ++i)
            gll16(xTimg + poff[i] + c * 32, (char*)Bp + ((i * 4 + wv) * 64) * 16);
        if (c == 0) stageA(0, 0, 0);
        __syncthreads();

        for (int t = 0; t < 9; ++t) {
            const int st = c * 9 + t;
            const int buf = st & 1;
            if (t < 8)      stageA(t + 1, c, buf ^ 1);
            else if (c < 3) stageA(0, c + 1, buf ^ 1);
            const int kh = t / 3, kw = t - kh * 3;
            short8 af[4], bf[7];
            #pragma unroll
            for (int a = 0; a < 4; ++a)
                af[a] = Ald[buf * 1024 + quad * 256 + wv * 64 + a * 16 + ln];
            #pragma unroll
            for (int b = 0; b < 7; ++b) {
                int dr = drb[b] + kh;
                int j = (kw == 1) ? (29 + cl0[b]) : (cl0[b] + (kw >> 1));
                bf[b] = Bp[quad * 513 + dr * 57 + j];
            }
            #pragma unroll
            for (int a = 0; a < 4; ++a)
                #pragma unroll
                for (int b = 0; b < 7; ++b)
                    acc[a][b] = __builtin_amdgcn_mfma_f32_16x16x32_bf16(
                        af[a], bf[b], acc[a][b], 0, 0, 0);
            __syncthreads();
        }
    }

    // epilogue: hist overlaid on Ald; clamp -> bf16 o1T (padded channels-last)
    uint_t* hist = (uint_t*)Ald;
    for (int i = tid; i < NBINS; i += 256) hist[i] = 0;
    __syncthreads();

    ushort_t* oimg = o1T + (size_t)n * O1_IMG;
    #pragma unroll
    for (int a = 0; a < 4; ++a) {
        int co = wv * 64 + a * 16 + quad * 4;
        #pragma unroll
        for (int b = 0; b < 7; ++b) {
            int p = b * 16 + ln;
            int h = r0 + p / 28, w = p % 28;
            ushort_t pk[4];
            #pragma unroll
            for (int r = 0; r < 4; ++r) {
                float v = acc[a][b][r];
                int bin = (int)((v - BIN_LO) * BIN_INV);
                bin = min(max(bin, 0), NBINS - 1);
                atomicAdd(&hist[bin], 1u);
                pk[r] = f2bf(fminf(fmaxf(v, 0.f), 1.f));
            }
            uint2 u; u.x = (uint_t)pk[0] | ((uint_t)pk[1] << 16);
            u.y = (uint_t)pk[2] | ((uint_t)pk[3] << 16);
            *(uint2*)(oimg + ((h + 1) * 30 + (w + 1)) * 256 + co) = u;
        }
    }

    __syncthreads();
    size_t blin = (size_t)bx * NBINS;
    for (int i = tid; i < NBINS; i += 256) bh[blin + i] = (ushort_t)hist[i];
}

// ---------------------------------------------------------------------------
// conv2 + fused identity, 8-row blocks (R5 structure; hist overlaid on Ad).
// ---------------------------------------------------------------------------
__global__ __launch_bounds__(256, 2) void conv2_mfma(
    const ushort_t* __restrict__ o1T, const ushort_t* __restrict__ xT,
    const ushort_t* __restrict__ wT2, float* __restrict__ fout,
    ushort_t* __restrict__ bh)
{
    const int bx = blockIdx.x;           // n*4 + rg
    const int by = blockIdx.y;
    const int tid = threadIdx.x;
    const int wv = tid >> 6, lane = tid & 63;
    const int ln = lane & 15, quad = lane >> 4;
    const int n = bx >> 2, rg = bx & 3, r0 = rg * 8;
    const int coh = wv & 1;
    const int pt  = wv >> 1;

    __shared__ short8 Ad[2 * 1024];      // 32 KB [buf][k8][co]
    __shared__ short8 Bp[2560];          // 40 KB patch [ci8][dr 10][col 32]

    f32x4 acc[4][7];
    #pragma unroll
    for (int a = 0; a < 4; ++a)
        #pragma unroll
        for (int b = 0; b < 7; ++b) acc[a][b] = (f32x4){0.f, 0.f, 0.f, 0.f};

    int prb[7], cl0[7], hlog[7];
    #pragma unroll
    for (int b = 0; b < 7; ++b) {
        int p = b * 16 + ln;
        int h = r0 + pt * 4 + p / 28;
        hlog[b] = h;
        prb[b] = (min(h, 27) - r0) * 32;
        cl0[b] = p % 28;
    }

    uint_t po[10];
    #pragma unroll
    for (int jj = 0; jj < 10; ++jj) {
        int f = (wv * 10 + jj) * 64 + lane;
        int ci8 = f / 320, rem = f % 320;
        int dr = rem >> 5, cl = rem & 31;
        po[jj] = (uint_t)(min(r0 + dr, 29) * O1_ROW + cl * 256 + ci8 * 8);
    }
    uint_t io[7];
    #pragma unroll
    for (int jj = 0; jj < 7; ++jj) {
        int f = (wv * 7 + jj) * 64 + lane;
        int ci8 = f / 224, pos = f % 224;
        int h = min(r0 + pos / 28, 27), w = pos % 28;
        io[jj] = (uint_t)(((2 * h + 1) * 57 + (2 * w + 1)) * 128 + ci8 * 8);
    }

    const ushort_t* Abase = wT2 + (size_t)(by * 128 + lane) * 2432;
    const ushort_t* o1img = o1T + (size_t)n * O1_IMG;
    const ushort_t* xTimg = xT + (size_t)n * XT_IMG;

    auto stageA = [&](int k0, int buf) {
        #pragma unroll
        for (int j = 0; j < 4; ++j)
            gll16(Abase + (j & 1) * 64 * 2432 + (wv * 2 + (j >> 1)) * 8 + k0,
                  (char*)Ad + buf * 16384 + (wv * 4 + j) * 1024);
    };

    for (int c = 0; c < 4; ++c) {
        #pragma unroll
        for (int jj = 0; jj < 10; ++jj)
            gll16(o1img + po[jj] + c * 64, (char*)Bp + (wv * 10 + jj) * 1024);
        if (c == 0) stageA(0, 0);
        __syncthreads();

        for (int t = 0; t < 9; ++t) {
            const int as = c * 9 + t;
            if (t < 8)      stageA((t + 1) * 256 + c * 64, (as + 1) & 1);
            else if (c < 3) stageA(c * 64 + 64, (as + 1) & 1);
            else            stageA(2304, (as + 1) & 1);
            const int ab = (as & 1) * 1024;
            const int kh = t / 3, kw = t - kh * 3;
            #pragma unroll
            for (int kk = 0; kk < 2; ++kk) {
                short8 af[4], bf[7];
                #pragma unroll
                for (int a = 0; a < 4; ++a)
                    af[a] = Ad[ab + (kk * 4 + quad) * 128 + coh * 64 + a * 16 + ln];
                #pragma unroll
                for (int b = 0; b < 7; ++b)
                    bf[b] = Bp[(kk * 4 + quad) * 320 + prb[b] + kh * 32 + cl0[b] + kw];
                #pragma unroll
                for (int a = 0; a < 4; ++a)
                    #pragma unroll
                    for (int b = 0; b < 7; ++b)
                        acc[a][b] = __builtin_amdgcn_mfma_f32_16x16x32_bf16(
                            af[a], bf[b], acc[a][b], 0, 0, 0);
            }
            __syncthreads();
        }
    }

    for (int cid = 0; cid < 2; ++cid) {
        #pragma unroll
        for (int jj = 0; jj < 7; ++jj)
            gll16(xTimg + io[jj] + cid * 64, (char*)Bp + (wv * 7 + jj) * 1024);
        __syncthreads();
        if (cid == 0) stageA(2368, 1);
        const int ab = ((36 + cid) & 1) * 1024;
        #pragma unroll
        for (int kk = 0; kk < 2; ++kk) {
            short8 af[4], bf[7];
            #pragma unroll
            for (int a = 0; a < 4; ++a)
                af[a] = Ad[ab + (kk * 4 + quad) * 128 + coh * 64 + a * 16 + ln];
            #pragma unroll
            for (int b = 0; b < 7; ++b)
                bf[b] = Bp[(kk * 4 + quad) * 224 + pt * 112 + b * 16 + ln];
            #pragma unroll
            for (int a = 0; a < 4; ++a)
                #pragma unroll
                for (int b = 0; b < 7; ++b)
                    acc[a][b] = __builtin_amdgcn_mfma_f32_16x16x32_bf16(
                        af[a], bf[b], acc[a][b], 0, 0, 0);
        }
        __syncthreads();
    }

    // epilogue: hist overlaid on Ad; clamp -> f32 out (NCHW)
    uint_t* hist = (uint_t*)Ad;
    for (int i = tid; i < NBINS; i += 256) hist[i] = 0;
    __syncthreads();

    #pragma unroll
    for (int a = 0; a < 4; ++a) {
        int co = by * 128 + coh * 64 + a * 16 + quad * 4;
        #pragma unroll
        for (int b = 0; b < 7; ++b) {
            if (hlog[b] <= 27) {
                #pragma unroll
                for (int r = 0; r < 4; ++r) {
                    float v = acc[a][b][r];
                    int bin = (int)((v - BIN_LO) * BIN_INV);
                    bin = min(max(bin, 0), NBINS - 1);
                    atomicAdd(&hist[bin], 1u);
                    fout[((size_t)(n * 256 + co + r)) * SPATIAL +
                         hlog[b] * 28 + cl0[b]] = fminf(fmaxf(v, 0.f), 1.f);
                }
            }
        }
    }

    __syncthreads();
    size_t blin = (size_t)(by * 256 + bx) * NBINS;
    for (int i = tid; i < NBINS; i += 256) bh[blin + i] = (ushort_t)hist[i];
}

// ---------------------------------------------------------------------------
// Reduce nblk per-block u16 histograms -> final u32 histogram
// ---------------------------------------------------------------------------
__global__ __launch_bounds__(256) void hreduce(
    const ushort_t* __restrict__ bh, uint_t* __restrict__ hf, int nblk)
{
    __shared__ uint_t p[256];
    int b0 = blockIdx.x * 64;
    int binl = threadIdx.x & 63, grp = threadIdx.x >> 6;
    uint_t s = 0;
    for (int j = grp; j < nblk; j += 4) s += bh[(size_t)j * NBINS + b0 + binl];
    p[threadIdx.x] = s;
    __syncthreads();
    if (threadIdx.x < 64)
        hf[b0 + threadIdx.x] = p[threadIdx.x] + p[64 + threadIdx.x] +
                               p[128 + threadIdx.x] + p[192 + threadIdx.x];
}

// ---------------------------------------------------------------------------
// Select 99 percentile values from the 2048-bin histogram
// ---------------------------------------------------------------------------
__global__ __launch_bounds__(1024) void select_k(
    const uint_t* __restrict__ hf, float* __restrict__ outp)
{
    __shared__ uint_t cs[1024];
    int t = threadIdx.x;
    uint_t s = hf[2 * t] + hf[2 * t + 1];
    cs[t] = s;
    __syncthreads();
    for (int d = 1; d < 1024; d <<= 1) {
        uint_t v = (t >= d) ? cs[t - d] : 0;
        __syncthreads();
        cs[t] += v;
        __syncthreads();
    }
    if (t >= 1 && t <= 99) {
        long long k = 1 + (long long)llrint(0.01 * (double)t * (double)(OUT_ELEMS - 1));
        int lo = 0, hi = 1023;
        while (lo < hi) { int mid = (lo + hi) >> 1; if ((long long)cs[mid] < k) lo = mid + 1; else hi = mid; }
        long long cum = (lo == 0) ? 0 : (long long)cs[lo - 1];
        int b = lo * 2;
        while (cum + (long long)hf[b] < k) { cum += hf[b]; ++b; }
        outp[t - 1] = BIN_LO + ((float)b + 0.5f) * BIN_W;
    }
}

// ---------------------------------------------------------------------------
extern "C" void kernel_launch(void* const* d_in, const int* in_sizes, int n_in,
                              void* d_out, int out_size, void* d_ws, size_t ws_size,
                              hipStream_t stream)
{
    const float* x   = (const float*)d_in[0];
    const float* w1  = (const float*)d_in[1];
    const float* w2  = (const float*)d_in[2];
    const float* wid = (const float*)d_in[3];
    float* out = (float*)d_out;

    char* ws = (char*)d_ws;
    ushort_t* xT  = (ushort_t*)ws;                         // 53,231,616 B (+4K pad)
    ushort_t* o1T = (ushort_t*)(ws + 53235712);            // 29,491,200 B (+4K pad)
    ushort_t* wT1 = (ushort_t*)(ws + 82731008);            //    589,824 B
    ushort_t* wT2 = (ushort_t*)(ws + 83320832);            //  1,245,184 B
    ushort_t* bhA = (ushort_t*)(ws + 84566016);            //  1,835,008 B (448 rows)
    ushort_t* bhB = (ushort_t*)(ws + 86401024);            //  2,097,152 B (512 rows)
    uint_t*   hfA = (uint_t*)  (ws + 88498176);            //      8,192 B
    uint_t*   hfB = (uint_t*)  (ws + 88506368);            //      8,192 B

    zwtrans<<<dim3(125, 64), 256, 0, stream>>>((uint_t*)xT, (uint_t*)o1T,
                                               w1, w2, wid, wT1, wT2);
    xtrans<<<dim3(14, 64), 256, 0, stream>>>(x, xT);

    conv1_mfma<<<448, 256, 0, stream>>>(xT, wT1, o1T, bhA);
    conv2_mfma<<<dim3(256, 2), 256, 0, stream>>>(o1T, xT, wT2, out, bhB);

    hreduce<<<32, 256, 0, stream>>>(bhA, hfA, 448);
    select_k<<<1, 1024, 0, stream>>>(hfA, out + OUT_ELEMS);
    hreduce<<<32, 256, 0, stream>>>(bhB, hfB, 512);
    select_k<<<1, 1024, 0, stream>>>(hfB, out + OUT_ELEMS + 99);
}